// Round 16
// baseline (66.160 us; speedup 1.0000x reference)
//
#include <hip/hip_runtime.h>
#include <hip/hip_bf16.h>
#include <math.h>

// Problem constants (fixed by reference)
constexpr int Bsz = 4;
constexpr int SEQ = 2048;
constexpr int DM  = 512;
constexpr int NH  = 8;
constexpr int HD  = 64;      // DM / NH
constexpr int LAG = 10;      // MAX_LAG
constexpr int MROWS = Bsz * SEQ;                        // 8192
constexpr size_t OUT0_ELEMS = (size_t)Bsz * SEQ * DM;   // 4,194,304
constexpr int NQKV = 3 * DM;                            // 1536

typedef __attribute__((ext_vector_type(8))) short short8;
typedef __attribute__((ext_vector_type(4))) float f32x4;
typedef __attribute__((ext_vector_type(16))) float f32x16;

__device__ __forceinline__ float bf2f(unsigned short u) {
  union { unsigned int i; float f; } x; x.i = (unsigned int)u << 16; return x.f;
}
__device__ __forceinline__ unsigned short f2bf(float f) {
  __hip_bfloat16 h = __float2bfloat16(f);
  return *(unsigned short*)&h;
}

// ---------------------------------------------------------------------------
// async global -> LDS, 16B per lane. LDS dest is wave-uniform base + lane*16.
// ---------------------------------------------------------------------------
__device__ __forceinline__ void gload_lds16(const void* g, void* l) {
  __builtin_amdgcn_global_load_lds(
      (const __attribute__((address_space(1))) unsigned int*)g,
      (__attribute__((address_space(3))) unsigned int*)l, 16, 0, 0);
}

// ---------------------------------------------------------------------------
// Prep (weights+bias only; x-cast now fused into qkv_gemm's A staging):
// blocks [0,1024) transpose+cast weights; block 1024 concatenates biases.
// ---------------------------------------------------------------------------
__global__ __launch_bounds__(256) void prep(
    const float* __restrict__ Wq, const float* __restrict__ Wk,
    const float* __restrict__ Wv, const float* __restrict__ Wo,
    const float* __restrict__ bq, const float* __restrict__ bk,
    const float* __restrict__ bv,
    __hip_bfloat16* __restrict__ Wtqkv, __hip_bfloat16* __restrict__ Wot,
    float* __restrict__ bcat) {
  __shared__ float t[32][33];
  const int blk = blockIdx.x;
  const int tid = threadIdx.x;
  if (blk < 1024) {
    const int z = blk >> 8, rem = blk & 255;
    const float* W = (z == 0) ? Wq : (z == 1) ? Wk : (z == 2) ? Wv : Wo;
    __hip_bfloat16* dst = (z < 3) ? (Wtqkv + (size_t)z * DM * DM) : Wot;
    const int n0 = (rem & 15) * 32, k0 = (rem >> 4) * 32;
    const int tx = tid & 31, ty = tid >> 5;
#pragma unroll
    for (int r = 0; r < 4; r++)
      t[ty + r * 8][tx] = W[(size_t)(k0 + ty + r * 8) * DM + n0 + tx];
    __syncthreads();
#pragma unroll
    for (int r = 0; r < 4; r++)
      dst[(size_t)(n0 + ty + r * 8) * DM + k0 + tx] =
          __float2bfloat16(t[tx][ty + r * 8]);
  } else {
    for (int i = tid; i < NQKV; i += 256)
      bcat[i] = (i < 512) ? bq[i] : (i < 1024) ? bk[i - 512] : bv[i - 1024];
  }
}

// ---------------------------------------------------------------------------
// QKV GEMM with FUSED x-cast: qkv = cast_bf16(x) @ Wtqkv^T + bcat, bf16 out.
// 256x192 tile, BK=64, 8 waves, 32x32x16 MFMA, stage-ahead dbuf.
// A staging: reg-staged f32 -> cvt bf16 -> XOR-swizzled ds_write_b128
//   (write-side swizzle == read-side swizzle; reads unchanged). Kills the
//   xb roundtrip and prep's 2048 x-cast blocks. (r6's version of this lost
//   at 128^2/4-wave; the 256x192/8-wave MFMA phase is 3x longer -> hides it.)
// B staging: global_load_lds + inverse-swizzled source (unchanged).
// attn_out zero-fill piggybacked: exactly 4 f32x4/thread/K-step (r13 best).
// ---------------------------------------------------------------------------
__global__ __launch_bounds__(512) void qkv_gemm(
    const float* __restrict__ X, const __hip_bfloat16* __restrict__ Bt,
    const float* __restrict__ bias, __hip_bfloat16* __restrict__ C,
    float* __restrict__ fill) {
  __shared__ __align__(16) char smem[114688];   // 2 x (32K A + 24K B)

  // XCD-aware bijective swizzle (grid 256, 32 M-tiles x 8 N-tiles)
  int lin = blockIdx.x;
  lin = (lin & 7) * 32 + (lin >> 3);
  const int bm = (lin >> 3) * 256;
  const int bn = (lin & 7) * 192;

  const int tid = threadIdx.x;
  const int lane = tid & 63, wave = tid >> 6;
  const int wr = wave >> 1, wc = wave & 1;      // 4M x 2N wave grid
  const int l31 = lane & 31, lhi = lane >> 5;
  const int gtid = blockIdx.x * 512 + tid;      // for fill
  constexpr int GSTRIDE = 256 * 512;            // 131072

  f32x16 acc[2][3] = {};

  // ---- A staging: reg-stage x f32 -> bf16 -> swizzled ds_write ----
  auto STAGE_A = [&](int buf, int k0) {
    char* base = smem + buf * 57344;
#pragma unroll
    for (int it = 0; it < 4; ++it) {
      const int g = it * 512 + tid;
      const int row = g >> 3, chl = g & 7;      // logical 8-elem chunk
      const float* src = X + (size_t)(bm + row) * DM + k0 + chl * 8;
      float4 lo = *(const float4*)src;
      float4 hi = *(const float4*)(src + 4);
      uint4 pk;
      pk.x = ((unsigned)f2bf(lo.y) << 16) | f2bf(lo.x);
      pk.y = ((unsigned)f2bf(lo.w) << 16) | f2bf(lo.z);
      pk.z = ((unsigned)f2bf(hi.y) << 16) | f2bf(hi.x);
      pk.w = ((unsigned)f2bf(hi.w) << 16) | f2bf(hi.z);
      // write-side XOR swizzle (matches read-side XOR)
      *(uint4*)(base + row * 128 + ((chl ^ (row & 7)) * 16)) = pk;
    }
  };
  // ---- B staging: global_load_lds + source swizzle ----
  auto STAGE_B = [&](int buf, int k0) {
    char* baseB = smem + buf * 57344 + 32768;
#pragma unroll
    for (int it = 0; it < 3; ++it) {
      const int g = it * 512 + tid;
      const int row = g >> 3, ch = g & 7;
      const int src_ch = ch ^ (row & 7);
      gload_lds16(Bt + (size_t)(bn + row) * DM + k0 + src_ch * 8,
                  baseB + (it * 512 + wave * 64) * 16);
    }
  };

  STAGE_B(0, 0);
  STAGE_A(0, 0);   // prologue

  for (int t = 0; t < 8; ++t) {
    __syncthreads();              // drains stage(t) (+ previous fills)
    if (t < 7) { STAGE_B((t + 1) & 1, (t + 1) * 64); STAGE_A((t + 1) & 1, (t + 1) * 64); }

    // fill: 4 f32x4 per thread per step (256*512*8*4 = 4,194,304 exact)
    {
      f32x4 z = {0.f, 0.f, 0.f, 0.f};
#pragma unroll
      for (int j = 0; j < 4; ++j)
        __builtin_nontemporal_store(z, (f32x4*)fill + gtid + (t * 4 + j) * GSTRIDE);
    }

    const char* As = smem + (t & 1) * 57344;
    const char* Bs = As + 32768;
#pragma unroll
    for (int kk = 0; kk < 4; ++kk) {   // 4 x K=16 sub-steps
      short8 a[2], b[3];
#pragma unroll
      for (int fi = 0; fi < 2; ++fi) {
        const int row = wr * 64 + fi * 32 + l31;
        const int ch = (kk * 2 + lhi) ^ (row & 7);
        a[fi] = *(const short8*)(As + row * 128 + ch * 16);
      }
#pragma unroll
      for (int fj = 0; fj < 3; ++fj) {
        const int row = wc * 96 + fj * 32 + l31;
        const int ch = (kk * 2 + lhi) ^ (row & 7);
        b[fj] = *(const short8*)(Bs + row * 128 + ch * 16);
      }
#pragma unroll
      for (int fi = 0; fi < 2; ++fi)
#pragma unroll
        for (int fj = 0; fj < 3; ++fj)
          acc[fi][fj] = __builtin_amdgcn_mfma_f32_32x32x16_bf16(
              a[fi], b[fj], acc[fi][fj], 0, 0, 0);
    }
  }

  // ---- epilogue: stage C in LDS (96 KB bf16), store coalesced ----
  __syncthreads();
  unsigned short (*Cs)[192] = (unsigned short (*)[192])smem;
#pragma unroll
  for (int fj = 0; fj < 3; ++fj) {
    const int col = wc * 96 + fj * 32 + l31;
    const float bv = bias[bn + col];
#pragma unroll
    for (int fi = 0; fi < 2; ++fi)
#pragma unroll
      for (int r = 0; r < 16; ++r) {
        const int row = wr * 64 + fi * 32 + (r & 3) + 8 * (r >> 2) + 4 * lhi;
        Cs[row][col] = f2bf(acc[fi][fj][r] + bv);
      }
  }
  __syncthreads();
#pragma unroll
  for (int it = 0; it < 12; ++it) {
    const int g = it * 512 + tid;       // 6144 chunks of 8 bf16, 24 per row
    const int row = g / 24, ch = g % 24;
    *(uint4*)(C + (size_t)(bm + row) * NQKV + bn + ch * 8) =
        *(const uint4*)&Cs[row][ch * 8];
  }
}

// ---------------------------------------------------------------------------
// O GEMM (r15: stage-ahead dbuf): out f32 = ctx bf16 @ Wot^T + bo.
// 128x128 tile, BK=64, 4 waves (2x2), 32x32x16 MFMA, LDS 64KB (2 blocks/CU).
// ---------------------------------------------------------------------------
__global__ __launch_bounds__(256) void o_gemm(
    const __hip_bfloat16* __restrict__ A, const __hip_bfloat16* __restrict__ Bt,
    const float* __restrict__ bias, float* __restrict__ C) {
  __shared__ __align__(16) char smem[65536];   // 2 x (16K A + 16K B)

  // XCD-aware bijective swizzle (grid 256, 64 M-tiles x 4 N-tiles)
  int lin = blockIdx.x;
  lin = (lin & 7) * 32 + (lin >> 3);
  const int bm = (lin >> 2) * 128;
  const int bn = (lin & 3) * 128;

  const int tid = threadIdx.x;
  const int lane = tid & 63, wave = tid >> 6;
  const int wr = wave >> 1, wc = wave & 1;
  const int l31 = lane & 31, lhi = lane >> 5;

  f32x16 acc[2][2] = {};

  auto STAGE = [&](int buf, int k0) {
    char* base = smem + buf * 32768;
#pragma unroll
    for (int it = 0; it < 4; ++it) {
      const int g = it * 256 + tid;
      const int row = g >> 3, ch = g & 7;
      const int src_ch = ch ^ (row & 7);
      gload_lds16(A + (size_t)(bm + row) * DM + k0 + src_ch * 8,
                  base + (it * 256 + wave * 64) * 16);
    }
    char* baseB = base + 16384;
#pragma unroll
    for (int it = 0; it < 4; ++it) {
      const int g = it * 256 + tid;
      const int row = g >> 3, ch = g & 7;
      const int src_ch = ch ^ (row & 7);
      gload_lds16(Bt + (size_t)(bn + row) * DM + k0 + src_ch * 8,
                  baseB + (it * 256 + wave * 64) * 16);
    }
  };

  STAGE(0, 0);

  for (int t = 0; t < 8; ++t) {
    __syncthreads();
    if (t < 7) STAGE((t + 1) & 1, (t + 1) * 64);

    const char* As = smem + (t & 1) * 32768;
    const char* Bs = As + 16384;
#pragma unroll
    for (int kk = 0; kk < 4; ++kk) {
      short8 a[2], b[2];
#pragma unroll
      for (int fi = 0; fi < 2; ++fi) {
        const int row = wr * 64 + fi * 32 + l31;
        const int ch = (kk * 2 + lhi) ^ (row & 7);
        a[fi] = *(const short8*)(As + row * 128 + ch * 16);
      }
#pragma unroll
      for (int fj = 0; fj < 2; ++fj) {
        const int row = wc * 64 + fj * 32 + l31;
        const int ch = (kk * 2 + lhi) ^ (row & 7);
        b[fj] = *(const short8*)(Bs + row * 128 + ch * 16);
      }
#pragma unroll
      for (int fi = 0; fi < 2; ++fi)
#pragma unroll
        for (int fj = 0; fj < 2; ++fj)
          acc[fi][fj] = __builtin_amdgcn_mfma_f32_32x32x16_bf16(
              a[fi], b[fj], acc[fi][fj], 0, 0, 0);
    }
  }

  // Epilogue: f32 staged through LDS in two 64-row halves (32 KB region).
  __syncthreads();
  float (*Cs)[128] = (float (*)[128])smem;
#pragma unroll
  for (int half = 0; half < 2; ++half) {
    if (wr == half) {
#pragma unroll
      for (int fj = 0; fj < 2; ++fj) {
        const float bv = bias[bn + wc * 64 + fj * 32 + l31];
        const int col = wc * 64 + fj * 32 + l31;
#pragma unroll
        for (int fi = 0; fi < 2; ++fi)
#pragma unroll
          for (int r = 0; r < 16; ++r) {
            const int row = fi * 32 + (r & 3) + 8 * (r >> 2) + 4 * lhi;
            Cs[row][col] = acc[fi][fj][r] + bv;
          }
      }
    }
    __syncthreads();
#pragma unroll
    for (int t = 0; t < 8; ++t) {
      const int g = t * 256 + tid;
      const int row = g >> 5, ch = g & 31;
      *(float4*)(C + (size_t)(bm + half * 64 + row) * DM + bn + ch * 4) =
          *(const float4*)&Cs[row][ch * 4];
    }
    __syncthreads();
  }
}

// ---------------------------------------------------------------------------
// Banded causal attention -- one wave per row (r15 best structure, __expf).
// attn_out pre-zeroed by QKV GEMM's fill; only band entries written here.
// ---------------------------------------------------------------------------
__global__ __launch_bounds__(256) void band_attn(
    const __hip_bfloat16* __restrict__ qkv, const float* __restrict__ decay_p,
    __hip_bfloat16* __restrict__ ctx, float* __restrict__ attn_out) {
  __shared__ float dlds[LAG + 1];
  const int tid = threadIdx.x;
  if (tid <= LAG) {
    float p = decay_p[tid];
    float sp = fmaxf(p, 0.0f) + log1pf(expf(-fabsf(p)));  // stable softplus
    dlds[tid] = -logf(sp + 1e-8f);
  }
  __syncthreads();

  const int blk = blockIdx.x;                  // 0..2047
  const int wave = tid >> 6, lane = tid & 63;
  const int bi = ((blk & 7) << 10) + ((blk >> 3) << 2) + wave;  // XCD-affine
  const int b = bi >> 11;
  const int i = bi & (SEQ - 1);
  const int jlo = (i >= LAG) ? (i - LAG) : 0;
  const int nj = i - jlo + 1;

  // q: 16B/lane (dims 8*lane..8*lane+7)
  const uint4 qu = *(const uint4*)(
      (const unsigned short*)(qkv + (size_t)bi * NQKV) + lane * 8);
  const unsigned short* qp = (const unsigned short*)&qu;
  float qf[8];
#pragma unroll
  for (int e = 0; e < 8; ++e) qf[e] = bf2f(qp[e]);

  // scores: 11 dots, all heads at once
  float s[LAG + 1];
#pragma unroll
  for (int jj = 0; jj <= LAG; ++jj) {
    const int j = jlo + jj;
    const bool ok = (j <= i);
    const int jc = ok ? j : i;
    const uint4 ku = *(const uint4*)(
        (const unsigned short*)(qkv + ((size_t)b * SEQ + jc) * NQKV + DM) + lane * 8);
    const unsigned short* kp = (const unsigned short*)&ku;
    float part = 0.0f;
#pragma unroll
    for (int e = 0; e < 8; ++e) part += qf[e] * bf2f(kp[e]);
    part += __shfl_xor(part, 1);
    part += __shfl_xor(part, 2);
    part += __shfl_xor(part, 4);   // lanes 8h..8h+7 now hold q_h . k_h
    s[jj] = ok ? (part * 0.125f + dlds[i - j]) : -1e30f;
  }

  // softmax over band (in-register; identical within each 8-lane head group)
  float mx = -1e30f;
#pragma unroll
  for (int jj = 0; jj <= LAG; ++jj) mx = fmaxf(mx, s[jj]);
  float sum = 0.0f;
#pragma unroll
  for (int jj = 0; jj <= LAG; ++jj) { s[jj] = __expf(s[jj] - mx); sum += s[jj]; }
  const float inv = 1.0f / sum;

  // PV accumulate (8 dims/lane); keep p in s[] for the head-mean
  float c[8] = {};
#pragma unroll
  for (int jj = 0; jj <= LAG; ++jj) {
    const float p = s[jj] * inv;
    s[jj] = p;
    const int j = jlo + jj;
    const int jc = (j <= i) ? j : i;
    const uint4 vu = *(const uint4*)(
        (const unsigned short*)(qkv + ((size_t)b * SEQ + jc) * NQKV + 2 * DM) + lane * 8);
    const unsigned short* vp = (const unsigned short*)&vu;
#pragma unroll
    for (int e = 0; e < 8; ++e) c[e] += p * bf2f(vp[e]);
  }

  // ctx store: pack 8 f32 -> 16B per lane (coalesced 1KB/row)
  unsigned short co[8];
#pragma unroll
  for (int e = 0; e < 8; ++e) co[e] = f2bf(c[e]);
  *(uint4*)((unsigned short*)(ctx + (size_t)bi * DM) + lane * 8) = *(const uint4*)co;

  // attn.mean over heads: reduce p across the 8 head groups (masks 8,16,32)
#pragma unroll
  for (int jj = 0; jj <= LAG; ++jj) {
    float a = s[jj];
    a += __shfl_xor(a, 8);
    a += __shfl_xor(a, 16);
    a += __shfl_xor(a, 32);        // all lanes: sum over 8 heads
    if (lane == jj && jj < nj)
      __builtin_nontemporal_store(a * 0.125f,
                                  attn_out + (size_t)bi * SEQ + jlo + jj);
  }
}

// ---------------------------------------------------------------------------
extern "C" void kernel_launch(void* const* d_in, const int* in_sizes, int n_in,
                              void* d_out, int out_size, void* d_ws, size_t ws_size,
                              hipStream_t stream) {
  const float* x   = (const float*)d_in[0];
  const float* Wq  = (const float*)d_in[1];
  const float* bq  = (const float*)d_in[2];
  const float* Wk  = (const float*)d_in[3];
  const float* bk  = (const float*)d_in[4];
  const float* Wv  = (const float*)d_in[5];
  const float* bv  = (const float*)d_in[6];
  const float* Wo  = (const float*)d_in[7];
  const float* bo  = (const float*)d_in[8];
  const float* dec = (const float*)d_in[9];

  float* out      = (float*)d_out;                 // [B,S,D]
  float* attn_out = out + OUT0_ELEMS;              // [B,S,S]

  // Workspace layout (16B-aligned), ~36 MB
  char* w = (char*)d_ws;
  __hip_bfloat16* Wtqkv = (__hip_bfloat16*)w;  w += (size_t)NQKV * DM * 2;
  __hip_bfloat16* Wot   = (__hip_bfloat16*)w;  w += (size_t)DM * DM * 2;
  float*          bcat  = (float*)w;           w += (size_t)NQKV * 4;
  __hip_bfloat16* qkv   = (__hip_bfloat16*)w;  w += (size_t)MROWS * NQKV * 2;
  __hip_bfloat16* ctxb  = (__hip_bfloat16*)w;

  prep<<<1025, 256, 0, stream>>>(Wq, Wk, Wv, Wo, bq, bk, bv,
                                 Wtqkv, Wot, bcat);

  // Fused x-cast + QKV projection (+ piggybacked attn_out fill)
  qkv_gemm<<<256, 512, 0, stream>>>(x, Wtqkv, bcat, qkv, attn_out);

  band_attn<<<2048, 256, 0, stream>>>(qkv, dec, ctxb, attn_out);

  // Output projection (dbuf stage-ahead): [8192,512] @ [512,512] -> f32 out
  o_gemm<<<256, 256, 0, stream>>>(ctxb, Wot, bo, out);
}

// Round 17
// 65.111 us; speedup vs baseline: 1.0161x; 1.0161x over previous
//
#include <hip/hip_runtime.h>
#include <hip/hip_bf16.h>
#include <math.h>

// Problem constants (fixed by reference)
constexpr int Bsz = 4;
constexpr int SEQ = 2048;
constexpr int DM  = 512;
constexpr int NH  = 8;
constexpr int HD  = 64;      // DM / NH
constexpr int LAG = 10;      // MAX_LAG
constexpr int MROWS = Bsz * SEQ;                        // 8192
constexpr size_t OUT0_ELEMS = (size_t)Bsz * SEQ * DM;   // 4,194,304
constexpr int NQKV = 3 * DM;                            // 1536

typedef __attribute__((ext_vector_type(8))) short short8;
typedef __attribute__((ext_vector_type(4))) float f32x4;
typedef __attribute__((ext_vector_type(16))) float f32x16;

__device__ __forceinline__ float bf2f(unsigned short u) {
  union { unsigned int i; float f; } x; x.i = (unsigned int)u << 16; return x.f;
}
__device__ __forceinline__ unsigned short f2bf(float f) {
  __hip_bfloat16 h = __float2bfloat16(f);
  return *(unsigned short*)&h;
}

// ---------------------------------------------------------------------------
// async global -> LDS, 16B per lane. LDS dest is wave-uniform base + lane*16.
// ---------------------------------------------------------------------------
__device__ __forceinline__ void gload_lds16(const void* g, void* l) {
  __builtin_amdgcn_global_load_lds(
      (const __attribute__((address_space(1))) unsigned int*)g,
      (__attribute__((address_space(3))) unsigned int*)l, 16, 0, 0);
}

// ---------------------------------------------------------------------------
// Fused prep: blocks [0,2048) cast x f32->bf16; [2048,3072) transpose+cast
// weights; block 3072 concatenates biases AND precomputes the 11-entry
// temporal-decay table (so band_attn needs no per-block transcendentals or
// barrier).
// ---------------------------------------------------------------------------
__global__ __launch_bounds__(256) void prep(
    const float* __restrict__ x, const float* __restrict__ Wq,
    const float* __restrict__ Wk, const float* __restrict__ Wv,
    const float* __restrict__ Wo, const float* __restrict__ bq,
    const float* __restrict__ bk, const float* __restrict__ bv,
    const float* __restrict__ decay_p,
    __hip_bfloat16* __restrict__ xb, __hip_bfloat16* __restrict__ Wtqkv,
    __hip_bfloat16* __restrict__ Wot, float* __restrict__ bcat,
    float* __restrict__ dldsg) {
  __shared__ float t[32][33];
  const int blk = blockIdx.x;
  const int tid = threadIdx.x;
  if (blk < 2048) {
    // x cast, 8 elems/thread
    size_t i = ((size_t)blk * 256 + tid) * 8;
    float4 a = *(const float4*)(x + i);
    float4 b = *(const float4*)(x + i + 4);
    union { unsigned short h[8]; uint4 u; } pk;
    pk.h[0] = f2bf(a.x); pk.h[1] = f2bf(a.y); pk.h[2] = f2bf(a.z); pk.h[3] = f2bf(a.w);
    pk.h[4] = f2bf(b.x); pk.h[5] = f2bf(b.y); pk.h[6] = f2bf(b.z); pk.h[7] = f2bf(b.w);
    *(uint4*)(xb + i) = pk.u;
  } else if (blk < 3072) {
    const int zb = blk - 2048;
    const int z = zb >> 8, rem = zb & 255;
    const float* W = (z == 0) ? Wq : (z == 1) ? Wk : (z == 2) ? Wv : Wo;
    __hip_bfloat16* dst = (z < 3) ? (Wtqkv + (size_t)z * DM * DM) : Wot;
    const int n0 = (rem & 15) * 32, k0 = (rem >> 4) * 32;
    const int tx = tid & 31, ty = tid >> 5;
#pragma unroll
    for (int r = 0; r < 4; r++)
      t[ty + r * 8][tx] = W[(size_t)(k0 + ty + r * 8) * DM + n0 + tx];
    __syncthreads();
#pragma unroll
    for (int r = 0; r < 4; r++)
      dst[(size_t)(n0 + ty + r * 8) * DM + k0 + tx] =
          __float2bfloat16(t[tx][ty + r * 8]);
  } else {
    for (int i = tid; i < NQKV; i += 256)
      bcat[i] = (i < 512) ? bq[i] : (i < 1024) ? bk[i - 512] : bv[i - 1024];
    if (tid < 12) {
      const int l = tid < 11 ? tid : 10;
      float p = decay_p[l];
      float sp = fmaxf(p, 0.0f) + log1pf(expf(-fabsf(p)));  // stable softplus
      dldsg[tid] = -logf(sp + 1e-8f);
    }
  }
}

// ---------------------------------------------------------------------------
// QKV GEMM (r15 best config): qkv = xb @ Wtqkv^T + bcat, bf16 out.
// 256x192 tile, BK=64, 8 waves, 32x32x16 MFMA, stage-ahead dbuf.
// attn_out zero-fill piggybacked: exactly 4 f32x4/thread/K-step.
// ---------------------------------------------------------------------------
__global__ __launch_bounds__(512) void qkv_gemm(
    const __hip_bfloat16* __restrict__ A, const __hip_bfloat16* __restrict__ Bt,
    const float* __restrict__ bias, __hip_bfloat16* __restrict__ C,
    float* __restrict__ fill) {
  __shared__ __align__(16) char smem[114688];   // 2 x (32K A + 24K B)

  // XCD-aware bijective swizzle (grid 256, 32 M-tiles x 8 N-tiles)
  int lin = blockIdx.x;
  lin = (lin & 7) * 32 + (lin >> 3);
  const int bm = (lin >> 3) * 256;
  const int bn = (lin & 7) * 192;

  const int tid = threadIdx.x;
  const int lane = tid & 63, wave = tid >> 6;
  const int wr = wave >> 1, wc = wave & 1;      // 4M x 2N wave grid
  const int l31 = lane & 31, lhi = lane >> 5;
  const int gtid = blockIdx.x * 512 + tid;      // for fill
  constexpr int GSTRIDE = 256 * 512;            // 131072

  f32x16 acc[2][3] = {};

  auto STAGE = [&](int buf, int k0) {
    char* base = smem + buf * 57344;
#pragma unroll
    for (int it = 0; it < 4; ++it) {
      const int g = it * 512 + tid;
      const int row = g >> 3, ch = g & 7;
      const int src_ch = ch ^ (row & 7);        // inverse swizzle on SOURCE
      gload_lds16(A + (size_t)(bm + row) * DM + k0 + src_ch * 8,
                  base + (it * 512 + wave * 64) * 16);
    }
    char* baseB = base + 32768;
#pragma unroll
    for (int it = 0; it < 3; ++it) {
      const int g = it * 512 + tid;
      const int row = g >> 3, ch = g & 7;
      const int src_ch = ch ^ (row & 7);
      gload_lds16(Bt + (size_t)(bn + row) * DM + k0 + src_ch * 8,
                  baseB + (it * 512 + wave * 64) * 16);
    }
  };

  STAGE(0, 0);  // prologue

  for (int t = 0; t < 8; ++t) {
    __syncthreads();              // drains stage(t) (+ previous fills)
    if (t < 7) STAGE((t + 1) & 1, (t + 1) * 64);

    // fill: 4 f32x4 per thread per step (256*512*8*4 = 4,194,304 exact)
    {
      f32x4 z = {0.f, 0.f, 0.f, 0.f};
#pragma unroll
      for (int j = 0; j < 4; ++j)
        __builtin_nontemporal_store(z, (f32x4*)fill + gtid + (t * 4 + j) * GSTRIDE);
    }

    const char* As = smem + (t & 1) * 57344;
    const char* Bs = As + 32768;
#pragma unroll
    for (int kk = 0; kk < 4; ++kk) {   // 4 x K=16 sub-steps
      short8 a[2], b[3];
#pragma unroll
      for (int fi = 0; fi < 2; ++fi) {
        const int row = wr * 64 + fi * 32 + l31;
        const int ch = (kk * 2 + lhi) ^ (row & 7);
        a[fi] = *(const short8*)(As + row * 128 + ch * 16);
      }
#pragma unroll
      for (int fj = 0; fj < 3; ++fj) {
        const int row = wc * 96 + fj * 32 + l31;
        const int ch = (kk * 2 + lhi) ^ (row & 7);
        b[fj] = *(const short8*)(Bs + row * 128 + ch * 16);
      }
#pragma unroll
      for (int fi = 0; fi < 2; ++fi)
#pragma unroll
        for (int fj = 0; fj < 3; ++fj)
          acc[fi][fj] = __builtin_amdgcn_mfma_f32_32x32x16_bf16(
              a[fi], b[fj], acc[fi][fj], 0, 0, 0);
    }
  }

  // ---- epilogue: stage C in LDS (96 KB bf16), store coalesced ----
  __syncthreads();
  unsigned short (*Cs)[192] = (unsigned short (*)[192])smem;
#pragma unroll
  for (int fj = 0; fj < 3; ++fj) {
    const int col = wc * 96 + fj * 32 + l31;
    const float bv = bias[bn + col];
#pragma unroll
    for (int fi = 0; fi < 2; ++fi)
#pragma unroll
      for (int r = 0; r < 16; ++r) {
        const int row = wr * 64 + fi * 32 + (r & 3) + 8 * (r >> 2) + 4 * lhi;
        Cs[row][col] = f2bf(acc[fi][fj][r] + bv);
      }
  }
  __syncthreads();
#pragma unroll
  for (int it = 0; it < 12; ++it) {
    const int g = it * 512 + tid;       // 6144 chunks of 8 bf16, 24 per row
    const int row = g / 24, ch = g % 24;
    *(uint4*)(C + (size_t)(bm + row) * NQKV + bn + ch * 8) =
        *(const uint4*)&Cs[row][ch * 8];
  }
}

// ---------------------------------------------------------------------------
// O GEMM (r15: stage-ahead dbuf): out f32 = ctx bf16 @ Wot^T + bo.
// 128x128 tile, BK=64, 4 waves (2x2), 32x32x16 MFMA, LDS 64KB (2 blocks/CU).
// ---------------------------------------------------------------------------
__global__ __launch_bounds__(256) void o_gemm(
    const __hip_bfloat16* __restrict__ A, const __hip_bfloat16* __restrict__ Bt,
    const float* __restrict__ bias, float* __restrict__ C) {
  __shared__ __align__(16) char smem[65536];   // 2 x (16K A + 16K B)

  // XCD-aware bijective swizzle (grid 256, 64 M-tiles x 4 N-tiles)
  int lin = blockIdx.x;
  lin = (lin & 7) * 32 + (lin >> 3);
  const int bm = (lin >> 2) * 128;
  const int bn = (lin & 3) * 128;

  const int tid = threadIdx.x;
  const int lane = tid & 63, wave = tid >> 6;
  const int wr = wave >> 1, wc = wave & 1;
  const int l31 = lane & 31, lhi = lane >> 5;

  f32x16 acc[2][2] = {};

  auto STAGE = [&](int buf, int k0) {
    char* base = smem + buf * 32768;
#pragma unroll
    for (int it = 0; it < 4; ++it) {
      const int g = it * 256 + tid;
      const int row = g >> 3, ch = g & 7;
      const int src_ch = ch ^ (row & 7);
      gload_lds16(A + (size_t)(bm + row) * DM + k0 + src_ch * 8,
                  base + (it * 256 + wave * 64) * 16);
    }
    char* baseB = base + 16384;
#pragma unroll
    for (int it = 0; it < 4; ++it) {
      const int g = it * 256 + tid;
      const int row = g >> 3, ch = g & 7;
      const int src_ch = ch ^ (row & 7);
      gload_lds16(Bt + (size_t)(bn + row) * DM + k0 + src_ch * 8,
                  baseB + (it * 256 + wave * 64) * 16);
    }
  };

  STAGE(0, 0);

  for (int t = 0; t < 8; ++t) {
    __syncthreads();
    if (t < 7) STAGE((t + 1) & 1, (t + 1) * 64);

    const char* As = smem + (t & 1) * 32768;
    const char* Bs = As + 16384;
#pragma unroll
    for (int kk = 0; kk < 4; ++kk) {
      short8 a[2], b[2];
#pragma unroll
      for (int fi = 0; fi < 2; ++fi) {
        const int row = wr * 64 + fi * 32 + l31;
        const int ch = (kk * 2 + lhi) ^ (row & 7);
        a[fi] = *(const short8*)(As + row * 128 + ch * 16);
      }
#pragma unroll
      for (int fj = 0; fj < 2; ++fj) {
        const int row = wc * 64 + fj * 32 + l31;
        const int ch = (kk * 2 + lhi) ^ (row & 7);
        b[fj] = *(const short8*)(Bs + row * 128 + ch * 16);
      }
#pragma unroll
      for (int fi = 0; fi < 2; ++fi)
#pragma unroll
        for (int fj = 0; fj < 2; ++fj)
          acc[fi][fj] = __builtin_amdgcn_mfma_f32_32x32x16_bf16(
              a[fi], b[fj], acc[fi][fj], 0, 0, 0);
    }
  }

  // Epilogue: f32 staged through LDS in two 64-row halves (32 KB region).
  __syncthreads();
  float (*Cs)[128] = (float (*)[128])smem;
#pragma unroll
  for (int half = 0; half < 2; ++half) {
    if (wr == half) {
#pragma unroll
      for (int fj = 0; fj < 2; ++fj) {
        const float bv = bias[bn + wc * 64 + fj * 32 + l31];
        const int col = wc * 64 + fj * 32 + l31;
#pragma unroll
        for (int fi = 0; fi < 2; ++fi)
#pragma unroll
          for (int r = 0; r < 16; ++r) {
            const int row = fi * 32 + (r & 3) + 8 * (r >> 2) + 4 * lhi;
            Cs[row][col] = acc[fi][fj][r] + bv;
          }
      }
    }
    __syncthreads();
#pragma unroll
    for (int t = 0; t < 8; ++t) {
      const int g = t * 256 + tid;
      const int row = g >> 5, ch = g & 31;
      *(float4*)(C + (size_t)(bm + half * 64 + row) * DM + bn + ch * 4) =
          *(const float4*)&Cs[row][ch * 4];
    }
    __syncthreads();
  }
}

// ---------------------------------------------------------------------------
// Banded causal attention -- one wave per row, BARRIER-FREE.
// Changes vs r15: (1) decay table precomputed in prep, loaded as 3 uniform
// float4 -> no LDS, no __syncthreads, no per-block transcendental startup;
// (2) loop indexed by lag l = i - j, so d[l] is compile-time-indexed (no
// scratch, rule #20) and the i-j arithmetic disappears. Off-band lanes clamp
// to row 0 with s = -1e30 -> p = 0 exactly (unchanged semantics).
// attn_out pre-zeroed by QKV GEMM's fill; only band entries written here.
// ---------------------------------------------------------------------------
__global__ __launch_bounds__(256) void band_attn(
    const __hip_bfloat16* __restrict__ qkv, const float* __restrict__ dldsg,
    __hip_bfloat16* __restrict__ ctx, float* __restrict__ attn_out) {
  const int tid = threadIdx.x;
  const int blk = blockIdx.x;                  // 0..2047
  const int wave = tid >> 6, lane = tid & 63;
  const int bi = ((blk & 7) << 10) + ((blk >> 3) << 2) + wave;  // XCD-affine
  const int b = bi >> 11;
  const int i = bi & (SEQ - 1);

  // decay table: 12 uniform floats (3 x float4), register-resident
  float d[12];
  {
    const float4 d0 = *(const float4*)(dldsg);
    const float4 d1 = *(const float4*)(dldsg + 4);
    const float4 d2 = *(const float4*)(dldsg + 8);
    d[0] = d0.x; d[1] = d0.y; d[2]  = d0.z; d[3]  = d0.w;
    d[4] = d1.x; d[5] = d1.y; d[6]  = d1.z; d[7]  = d1.w;
    d[8] = d2.x; d[9] = d2.y; d[10] = d2.z; d[11] = d2.w;
  }

  // q: 16B/lane (dims 8*lane..8*lane+7)
  const uint4 qu = *(const uint4*)(
      (const unsigned short*)(qkv + (size_t)bi * NQKV) + lane * 8);
  const unsigned short* qp = (const unsigned short*)&qu;
  float qf[8];
#pragma unroll
  for (int e = 0; e < 8; ++e) qf[e] = bf2f(qp[e]);

  // scores by lag l (j = i - l): 11 dots, all heads at once
  float s[LAG + 1];
#pragma unroll
  for (int l = 0; l <= LAG; ++l) {
    const int j = i - l;
    const bool ok = (j >= 0);
    const int jc = ok ? j : 0;
    const uint4 ku = *(const uint4*)(
        (const unsigned short*)(qkv + ((size_t)b * SEQ + jc) * NQKV + DM) + lane * 8);
    const unsigned short* kp = (const unsigned short*)&ku;
    float part = 0.0f;
#pragma unroll
    for (int e = 0; e < 8; ++e) part += qf[e] * bf2f(kp[e]);
    part += __shfl_xor(part, 1);
    part += __shfl_xor(part, 2);
    part += __shfl_xor(part, 4);   // lanes 8h..8h+7 now hold q_h . k_h
    s[l] = ok ? (part * 0.125f + d[l]) : -1e30f;
  }

  // softmax over band (in-register; identical within each 8-lane head group)
  float mx = -1e30f;
#pragma unroll
  for (int l = 0; l <= LAG; ++l) mx = fmaxf(mx, s[l]);
  float sum = 0.0f;
#pragma unroll
  for (int l = 0; l <= LAG; ++l) { s[l] = __expf(s[l] - mx); sum += s[l]; }
  const float inv = 1.0f / sum;

  // PV accumulate (8 dims/lane); keep p in s[] for the head-mean
  float c[8] = {};
#pragma unroll
  for (int l = 0; l <= LAG; ++l) {
    const float p = s[l] * inv;
    s[l] = p;
    const int j = i - l;
    const int jc = (j >= 0) ? j : 0;
    const uint4 vu = *(const uint4*)(
        (const unsigned short*)(qkv + ((size_t)b * SEQ + jc) * NQKV + 2 * DM) + lane * 8);
    const unsigned short* vp = (const unsigned short*)&vu;
#pragma unroll
    for (int e = 0; e < 8; ++e) c[e] += p * bf2f(vp[e]);
  }

  // ctx store: pack 8 f32 -> 16B per lane (coalesced 1KB/row)
  unsigned short co[8];
#pragma unroll
  for (int e = 0; e < 8; ++e) co[e] = f2bf(c[e]);
  *(uint4*)((unsigned short*)(ctx + (size_t)bi * DM) + lane * 8) = *(const uint4*)co;

  // attn.mean over heads: reduce p across the 8 head groups (masks 8,16,32);
  // lane l stores the lag-l entry at column i-l.
#pragma unroll
  for (int l = 0; l <= LAG; ++l) {
    float a = s[l];
    a += __shfl_xor(a, 8);
    a += __shfl_xor(a, 16);
    a += __shfl_xor(a, 32);        // all lanes: sum over 8 heads
    if (lane == l && l <= i)
      __builtin_nontemporal_store(a * 0.125f,
                                  attn_out + (size_t)bi * SEQ + (i - l));
  }
}

// ---------------------------------------------------------------------------
extern "C" void kernel_launch(void* const* d_in, const int* in_sizes, int n_in,
                              void* d_out, int out_size, void* d_ws, size_t ws_size,
                              hipStream_t stream) {
  const float* x   = (const float*)d_in[0];
  const float* Wq  = (const float*)d_in[1];
  const float* bq  = (const float*)d_in[2];
  const float* Wk  = (const float*)d_in[3];
  const float* bk  = (const float*)d_in[4];
  const float* Wv  = (const float*)d_in[5];
  const float* bv  = (const float*)d_in[6];
  const float* Wo  = (const float*)d_in[7];
  const float* bo  = (const float*)d_in[8];
  const float* dec = (const float*)d_in[9];

  float* out      = (float*)d_out;                 // [B,S,D]
  float* attn_out = out + OUT0_ELEMS;              // [B,S,S]

  // Workspace layout (16B-aligned), ~44 MB
  char* w = (char*)d_ws;
  __hip_bfloat16* xb    = (__hip_bfloat16*)w;  w += (size_t)MROWS * DM * 2;
  __hip_bfloat16* Wtqkv = (__hip_bfloat16*)w;  w += (size_t)NQKV * DM * 2;
  __hip_bfloat16* Wot   = (__hip_bfloat16*)w;  w += (size_t)DM * DM * 2;
  float*          bcat  = (float*)w;           w += (size_t)NQKV * 4;
  float*          dldsg = (float*)w;           w += 16 * 4;
  __hip_bfloat16* qkv   = (__hip_bfloat16*)w;  w += (size_t)MROWS * NQKV * 2;
  __hip_bfloat16* ctxb  = (__hip_bfloat16*)w;

  prep<<<3073, 256, 0, stream>>>(x, Wq, Wk, Wv, Wo, bq, bk, bv, dec,
                                 xb, Wtqkv, Wot, bcat, dldsg);

  // Fused QKV projection (256x192 tile, dbuf stage-ahead, + attn_out fill)
  qkv_gemm<<<256, 512, 0, stream>>>(xb, Wtqkv, bcat, qkv, attn_out);

  band_attn<<<2048, 256, 0, stream>>>(qkv, dldsg, ctxb, attn_out);

  // Output projection (dbuf stage-ahead): [8192,512] @ [512,512] -> f32 out
  o_gemm<<<256, 256, 0, stream>>>(ctxb, Wot, bo, out);
}

// Round 18
// 63.783 us; speedup vs baseline: 1.0373x; 1.0208x over previous
//
#include <hip/hip_runtime.h>
#include <hip/hip_bf16.h>
#include <math.h>

// Problem constants (fixed by reference)
constexpr int Bsz = 4;
constexpr int SEQ = 2048;
constexpr int DM  = 512;
constexpr int NH  = 8;
constexpr int HD  = 64;      // DM / NH
constexpr int LAG = 10;      // MAX_LAG
constexpr int MROWS = Bsz * SEQ;                        // 8192
constexpr size_t OUT0_ELEMS = (size_t)Bsz * SEQ * DM;   // 4,194,304
constexpr int NQKV = 3 * DM;                            // 1536

typedef __attribute__((ext_vector_type(8))) short short8;
typedef __attribute__((ext_vector_type(4))) float f32x4;
typedef __attribute__((ext_vector_type(16))) float f32x16;

__device__ __forceinline__ float bf2f(unsigned short u) {
  union { unsigned int i; float f; } x; x.i = (unsigned int)u << 16; return x.f;
}
__device__ __forceinline__ unsigned short f2bf(float f) {
  __hip_bfloat16 h = __float2bfloat16(f);
  return *(unsigned short*)&h;
}

// ---------------------------------------------------------------------------
// async global -> LDS, 16B per lane. LDS dest is wave-uniform base + lane*16.
// ---------------------------------------------------------------------------
__device__ __forceinline__ void gload_lds16(const void* g, void* l) {
  __builtin_amdgcn_global_load_lds(
      (const __attribute__((address_space(1))) unsigned int*)g,
      (__attribute__((address_space(3))) unsigned int*)l, 16, 0, 0);
}

// ---------------------------------------------------------------------------
// Fused prep: blocks [0,2048) cast x f32->bf16; [2048,3072) transpose+cast
// weights; block 3072 concatenates biases.
// ---------------------------------------------------------------------------
__global__ __launch_bounds__(256) void prep(
    const float* __restrict__ x, const float* __restrict__ Wq,
    const float* __restrict__ Wk, const float* __restrict__ Wv,
    const float* __restrict__ Wo, const float* __restrict__ bq,
    const float* __restrict__ bk, const float* __restrict__ bv,
    __hip_bfloat16* __restrict__ xb, __hip_bfloat16* __restrict__ Wtqkv,
    __hip_bfloat16* __restrict__ Wot, float* __restrict__ bcat) {
  __shared__ float t[32][33];
  const int blk = blockIdx.x;
  const int tid = threadIdx.x;
  if (blk < 2048) {
    // x cast, 8 elems/thread
    size_t i = ((size_t)blk * 256 + tid) * 8;
    float4 a = *(const float4*)(x + i);
    float4 b = *(const float4*)(x + i + 4);
    union { unsigned short h[8]; uint4 u; } pk;
    pk.h[0] = f2bf(a.x); pk.h[1] = f2bf(a.y); pk.h[2] = f2bf(a.z); pk.h[3] = f2bf(a.w);
    pk.h[4] = f2bf(b.x); pk.h[5] = f2bf(b.y); pk.h[6] = f2bf(b.z); pk.h[7] = f2bf(b.w);
    *(uint4*)(xb + i) = pk.u;
  } else if (blk < 3072) {
    const int zb = blk - 2048;
    const int z = zb >> 8, rem = zb & 255;
    const float* W = (z == 0) ? Wq : (z == 1) ? Wk : (z == 2) ? Wv : Wo;
    __hip_bfloat16* dst = (z < 3) ? (Wtqkv + (size_t)z * DM * DM) : Wot;
    const int n0 = (rem & 15) * 32, k0 = (rem >> 4) * 32;
    const int tx = tid & 31, ty = tid >> 5;
#pragma unroll
    for (int r = 0; r < 4; r++)
      t[ty + r * 8][tx] = W[(size_t)(k0 + ty + r * 8) * DM + n0 + tx];
    __syncthreads();
#pragma unroll
    for (int r = 0; r < 4; r++)
      dst[(size_t)(n0 + ty + r * 8) * DM + k0 + tx] =
          __float2bfloat16(t[tx][ty + r * 8]);
  } else {
    for (int i = tid; i < NQKV; i += 256)
      bcat[i] = (i < 512) ? bq[i] : (i < 1024) ? bk[i - 512] : bv[i - 1024];
  }
}

// ---------------------------------------------------------------------------
// QKV GEMM (r15 best config): qkv = xb @ Wtqkv^T + bcat, bf16 out.
// 256x192 tile, BK=64, 8 waves, 32x32x16 MFMA, stage-ahead dbuf.
// attn_out zero-fill piggybacked: exactly 4 f32x4/thread/K-step.
// ---------------------------------------------------------------------------
__global__ __launch_bounds__(512) void qkv_gemm(
    const __hip_bfloat16* __restrict__ A, const __hip_bfloat16* __restrict__ Bt,
    const float* __restrict__ bias, __hip_bfloat16* __restrict__ C,
    float* __restrict__ fill) {
  __shared__ __align__(16) char smem[114688];   // 2 x (32K A + 24K B)

  // XCD-aware bijective swizzle (grid 256, 32 M-tiles x 8 N-tiles)
  int lin = blockIdx.x;
  lin = (lin & 7) * 32 + (lin >> 3);
  const int bm = (lin >> 3) * 256;
  const int bn = (lin & 7) * 192;

  const int tid = threadIdx.x;
  const int lane = tid & 63, wave = tid >> 6;
  const int wr = wave >> 1, wc = wave & 1;      // 4M x 2N wave grid
  const int l31 = lane & 31, lhi = lane >> 5;
  const int gtid = blockIdx.x * 512 + tid;      // for fill
  constexpr int GSTRIDE = 256 * 512;            // 131072

  f32x16 acc[2][3] = {};

  auto STAGE = [&](int buf, int k0) {
    char* base = smem + buf * 57344;
#pragma unroll
    for (int it = 0; it < 4; ++it) {
      const int g = it * 512 + tid;
      const int row = g >> 3, ch = g & 7;
      const int src_ch = ch ^ (row & 7);        // inverse swizzle on SOURCE
      gload_lds16(A + (size_t)(bm + row) * DM + k0 + src_ch * 8,
                  base + (it * 512 + wave * 64) * 16);
    }
    char* baseB = base + 32768;
#pragma unroll
    for (int it = 0; it < 3; ++it) {
      const int g = it * 512 + tid;
      const int row = g >> 3, ch = g & 7;
      const int src_ch = ch ^ (row & 7);
      gload_lds16(Bt + (size_t)(bn + row) * DM + k0 + src_ch * 8,
                  baseB + (it * 512 + wave * 64) * 16);
    }
  };

  STAGE(0, 0);  // prologue

  for (int t = 0; t < 8; ++t) {
    __syncthreads();              // drains stage(t) (+ previous fills)
    if (t < 7) STAGE((t + 1) & 1, (t + 1) * 64);

    // fill: 4 f32x4 per thread per step (256*512*8*4 = 4,194,304 exact)
    {
      f32x4 z = {0.f, 0.f, 0.f, 0.f};
#pragma unroll
      for (int j = 0; j < 4; ++j)
        __builtin_nontemporal_store(z, (f32x4*)fill + gtid + (t * 4 + j) * GSTRIDE);
    }

    const char* As = smem + (t & 1) * 57344;
    const char* Bs = As + 32768;
#pragma unroll
    for (int kk = 0; kk < 4; ++kk) {   // 4 x K=16 sub-steps
      short8 a[2], b[3];
#pragma unroll
      for (int fi = 0; fi < 2; ++fi) {
        const int row = wr * 64 + fi * 32 + l31;
        const int ch = (kk * 2 + lhi) ^ (row & 7);
        a[fi] = *(const short8*)(As + row * 128 + ch * 16);
      }
#pragma unroll
      for (int fj = 0; fj < 3; ++fj) {
        const int row = wc * 96 + fj * 32 + l31;
        const int ch = (kk * 2 + lhi) ^ (row & 7);
        b[fj] = *(const short8*)(Bs + row * 128 + ch * 16);
      }
#pragma unroll
      for (int fi = 0; fi < 2; ++fi)
#pragma unroll
        for (int fj = 0; fj < 3; ++fj)
          acc[fi][fj] = __builtin_amdgcn_mfma_f32_32x32x16_bf16(
              a[fi], b[fj], acc[fi][fj], 0, 0, 0);
    }
  }

  // ---- epilogue: stage C in LDS (96 KB bf16), store coalesced ----
  __syncthreads();
  unsigned short (*Cs)[192] = (unsigned short (*)[192])smem;
#pragma unroll
  for (int fj = 0; fj < 3; ++fj) {
    const int col = wc * 96 + fj * 32 + l31;
    const float bv = bias[bn + col];
#pragma unroll
    for (int fi = 0; fi < 2; ++fi)
#pragma unroll
      for (int r = 0; r < 16; ++r) {
        const int row = wr * 64 + fi * 32 + (r & 3) + 8 * (r >> 2) + 4 * lhi;
        Cs[row][col] = f2bf(acc[fi][fj][r] + bv);
      }
  }
  __syncthreads();
#pragma unroll
  for (int it = 0; it < 12; ++it) {
    const int g = it * 512 + tid;       // 6144 chunks of 8 bf16, 24 per row
    const int row = g / 24, ch = g % 24;
    *(uint4*)(C + (size_t)(bm + row) * NQKV + bn + ch * 8) =
        *(const uint4*)&Cs[row][ch * 8];
  }
}

// ---------------------------------------------------------------------------
// O GEMM (r15 dbuf + NEW nontemporal out-stores; out is never re-read, so
// keep it out of L2 to protect ctx/Wot residency).
// 128x128 tile, BK=64, 4 waves (2x2), 32x32x16 MFMA, LDS 64KB.
// ---------------------------------------------------------------------------
__global__ __launch_bounds__(256) void o_gemm(
    const __hip_bfloat16* __restrict__ A, const __hip_bfloat16* __restrict__ Bt,
    const float* __restrict__ bias, float* __restrict__ C) {
  __shared__ __align__(16) char smem[65536];   // 2 x (16K A + 16K B)

  // XCD-aware bijective swizzle (grid 256, 64 M-tiles x 4 N-tiles)
  int lin = blockIdx.x;
  lin = (lin & 7) * 32 + (lin >> 3);
  const int bm = (lin >> 2) * 128;
  const int bn = (lin & 3) * 128;

  const int tid = threadIdx.x;
  const int lane = tid & 63, wave = tid >> 6;
  const int wr = wave >> 1, wc = wave & 1;
  const int l31 = lane & 31, lhi = lane >> 5;

  f32x16 acc[2][2] = {};

  auto STAGE = [&](int buf, int k0) {
    char* base = smem + buf * 32768;
#pragma unroll
    for (int it = 0; it < 4; ++it) {
      const int g = it * 256 + tid;
      const int row = g >> 3, ch = g & 7;
      const int src_ch = ch ^ (row & 7);
      gload_lds16(A + (size_t)(bm + row) * DM + k0 + src_ch * 8,
                  base + (it * 256 + wave * 64) * 16);
    }
    char* baseB = base + 16384;
#pragma unroll
    for (int it = 0; it < 4; ++it) {
      const int g = it * 256 + tid;
      const int row = g >> 3, ch = g & 7;
      const int src_ch = ch ^ (row & 7);
      gload_lds16(Bt + (size_t)(bn + row) * DM + k0 + src_ch * 8,
                  baseB + (it * 256 + wave * 64) * 16);
    }
  };

  STAGE(0, 0);

  for (int t = 0; t < 8; ++t) {
    __syncthreads();
    if (t < 7) STAGE((t + 1) & 1, (t + 1) * 64);

    const char* As = smem + (t & 1) * 32768;
    const char* Bs = As + 16384;
#pragma unroll
    for (int kk = 0; kk < 4; ++kk) {
      short8 a[2], b[2];
#pragma unroll
      for (int fi = 0; fi < 2; ++fi) {
        const int row = wr * 64 + fi * 32 + l31;
        const int ch = (kk * 2 + lhi) ^ (row & 7);
        a[fi] = *(const short8*)(As + row * 128 + ch * 16);
      }
#pragma unroll
      for (int fj = 0; fj < 2; ++fj) {
        const int row = wc * 64 + fj * 32 + l31;
        const int ch = (kk * 2 + lhi) ^ (row & 7);
        b[fj] = *(const short8*)(Bs + row * 128 + ch * 16);
      }
#pragma unroll
      for (int fi = 0; fi < 2; ++fi)
#pragma unroll
        for (int fj = 0; fj < 2; ++fj)
          acc[fi][fj] = __builtin_amdgcn_mfma_f32_32x32x16_bf16(
              a[fi], b[fj], acc[fi][fj], 0, 0, 0);
    }
  }

  // Epilogue: f32 staged through LDS in two 64-row halves (32 KB region).
  __syncthreads();
  float (*Cs)[128] = (float (*)[128])smem;
#pragma unroll
  for (int half = 0; half < 2; ++half) {
    if (wr == half) {
#pragma unroll
      for (int fj = 0; fj < 2; ++fj) {
        const float bv = bias[bn + wc * 64 + fj * 32 + l31];
        const int col = wc * 64 + fj * 32 + l31;
#pragma unroll
        for (int fi = 0; fi < 2; ++fi)
#pragma unroll
          for (int r = 0; r < 16; ++r) {
            const int row = fi * 32 + (r & 3) + 8 * (r >> 2) + 4 * lhi;
            Cs[row][col] = acc[fi][fj][r] + bv;
          }
      }
    }
    __syncthreads();
#pragma unroll
    for (int t = 0; t < 8; ++t) {
      const int g = t * 256 + tid;
      const int row = g >> 5, ch = g & 31;
      const f32x4 v = *(const f32x4*)&Cs[row][ch * 4];
      __builtin_nontemporal_store(
          v, (f32x4*)(C + (size_t)(bm + half * 64 + row) * DM + bn + ch * 4));
    }
    __syncthreads();
  }
}

// ---------------------------------------------------------------------------
// Banded causal attention -- one wave per row (r15 best-measured structure).
// attn_out pre-zeroed by QKV GEMM's fill; only band entries written here.
// ---------------------------------------------------------------------------
__global__ __launch_bounds__(256) void band_attn(
    const __hip_bfloat16* __restrict__ qkv, const float* __restrict__ decay_p,
    __hip_bfloat16* __restrict__ ctx, float* __restrict__ attn_out) {
  __shared__ float dlds[LAG + 1];
  const int tid = threadIdx.x;
  if (tid <= LAG) {
    float p = decay_p[tid];
    float sp = fmaxf(p, 0.0f) + log1pf(expf(-fabsf(p)));  // stable softplus
    dlds[tid] = -logf(sp + 1e-8f);
  }
  __syncthreads();

  const int blk = blockIdx.x;                  // 0..2047
  const int wave = tid >> 6, lane = tid & 63;
  const int bi = ((blk & 7) << 10) + ((blk >> 3) << 2) + wave;  // XCD-affine
  const int b = bi >> 11;
  const int i = bi & (SEQ - 1);
  const int jlo = (i >= LAG) ? (i - LAG) : 0;
  const int nj = i - jlo + 1;

  // q: 16B/lane (dims 8*lane..8*lane+7)
  const uint4 qu = *(const uint4*)(
      (const unsigned short*)(qkv + (size_t)bi * NQKV) + lane * 8);
  const unsigned short* qp = (const unsigned short*)&qu;
  float qf[8];
#pragma unroll
  for (int e = 0; e < 8; ++e) qf[e] = bf2f(qp[e]);

  // scores: 11 dots, all heads at once
  float s[LAG + 1];
#pragma unroll
  for (int jj = 0; jj <= LAG; ++jj) {
    const int j = jlo + jj;
    const bool ok = (j <= i);
    const int jc = ok ? j : i;
    const uint4 ku = *(const uint4*)(
        (const unsigned short*)(qkv + ((size_t)b * SEQ + jc) * NQKV + DM) + lane * 8);
    const unsigned short* kp = (const unsigned short*)&ku;
    float part = 0.0f;
#pragma unroll
    for (int e = 0; e < 8; ++e) part += qf[e] * bf2f(kp[e]);
    part += __shfl_xor(part, 1);
    part += __shfl_xor(part, 2);
    part += __shfl_xor(part, 4);   // lanes 8h..8h+7 now hold q_h . k_h
    s[jj] = ok ? (part * 0.125f + dlds[i - j]) : -1e30f;
  }

  // softmax over band (in-register; identical within each 8-lane head group)
  float mx = -1e30f;
#pragma unroll
  for (int jj = 0; jj <= LAG; ++jj) mx = fmaxf(mx, s[jj]);
  float sum = 0.0f;
#pragma unroll
  for (int jj = 0; jj <= LAG; ++jj) { s[jj] = __expf(s[jj] - mx); sum += s[jj]; }
  const float inv = 1.0f / sum;

  // PV accumulate (8 dims/lane); keep p in s[] for the head-mean
  float c[8] = {};
#pragma unroll
  for (int jj = 0; jj <= LAG; ++jj) {
    const float p = s[jj] * inv;
    s[jj] = p;
    const int j = jlo + jj;
    const int jc = (j <= i) ? j : i;
    const uint4 vu = *(const uint4*)(
        (const unsigned short*)(qkv + ((size_t)b * SEQ + jc) * NQKV + 2 * DM) + lane * 8);
    const unsigned short* vp = (const unsigned short*)&vu;
#pragma unroll
    for (int e = 0; e < 8; ++e) c[e] += p * bf2f(vp[e]);
  }

  // ctx store: pack 8 f32 -> 16B per lane (coalesced 1KB/row)
  unsigned short co[8];
#pragma unroll
  for (int e = 0; e < 8; ++e) co[e] = f2bf(c[e]);
  *(uint4*)((unsigned short*)(ctx + (size_t)bi * DM) + lane * 8) = *(const uint4*)co;

  // attn.mean over heads: reduce p across the 8 head groups (masks 8,16,32)
#pragma unroll
  for (int jj = 0; jj <= LAG; ++jj) {
    float a = s[jj];
    a += __shfl_xor(a, 8);
    a += __shfl_xor(a, 16);
    a += __shfl_xor(a, 32);        // all lanes: sum over 8 heads
    if (lane == jj && jj < nj)
      __builtin_nontemporal_store(a * 0.125f,
                                  attn_out + (size_t)bi * SEQ + jlo + jj);
  }
}

// ---------------------------------------------------------------------------
extern "C" void kernel_launch(void* const* d_in, const int* in_sizes, int n_in,
                              void* d_out, int out_size, void* d_ws, size_t ws_size,
                              hipStream_t stream) {
  const float* x   = (const float*)d_in[0];
  const float* Wq  = (const float*)d_in[1];
  const float* bq  = (const float*)d_in[2];
  const float* Wk  = (const float*)d_in[3];
  const float* bk  = (const float*)d_in[4];
  const float* Wv  = (const float*)d_in[5];
  const float* bv  = (const float*)d_in[6];
  const float* Wo  = (const float*)d_in[7];
  const float* bo  = (const float*)d_in[8];
  const float* dec = (const float*)d_in[9];

  float* out      = (float*)d_out;                 // [B,S,D]
  float* attn_out = out + OUT0_ELEMS;              // [B,S,S]

  // Workspace layout (16B-aligned), ~44 MB
  char* w = (char*)d_ws;
  __hip_bfloat16* xb    = (__hip_bfloat16*)w;  w += (size_t)MROWS * DM * 2;
  __hip_bfloat16* Wtqkv = (__hip_bfloat16*)w;  w += (size_t)NQKV * DM * 2;
  __hip_bfloat16* Wot   = (__hip_bfloat16*)w;  w += (size_t)DM * DM * 2;
  float*          bcat  = (float*)w;           w += (size_t)NQKV * 4;
  __hip_bfloat16* qkv   = (__hip_bfloat16*)w;  w += (size_t)MROWS * NQKV * 2;
  __hip_bfloat16* ctxb  = (__hip_bfloat16*)w;

  prep<<<3073, 256, 0, stream>>>(x, Wq, Wk, Wv, Wo, bq, bk, bv,
                                 xb, Wtqkv, Wot, bcat);

  // Fused QKV projection (256x192 tile, dbuf stage-ahead, + attn_out fill)
  qkv_gemm<<<256, 512, 0, stream>>>(xb, Wtqkv, bcat, qkv, attn_out);

  band_attn<<<2048, 256, 0, stream>>>(qkv, dec, ctxb, attn_out);

  // Output projection (dbuf stage-ahead, nontemporal out)
  o_gemm<<<256, 256, 0, stream>>>(ctxb, Wot, bo, out);
}